// Round 18
// baseline (392.998 us; speedup 1.0000x reference)
//
#include <hip/hip_runtime.h>
#include <stdint.h>

// GeneDynamics: out = -x + (A @ x^2) / (x^2 + 1)
// v14: v13 with KC=128 -> 24 KiB tile -> 6 blocks/CU (24 waves/CU).
//      KSPLIT=4 keeps all CUs saturated. Same staging/read swizzles
//      re-derived for KC=128; NT on stream-once A loads.

#define NN 16384
#define DIM 16
#define TPB 256                // 4 waves
#define ROWS 32                // rows per block
#define NRB 512                // NN / ROWS
#define KSPLIT 4
#define KRANGE 4096            // NN / KSPLIT
#define KC 128                 // k per chunk (512 B per row per chunk)
#define NCH 32                 // KRANGE / KC

// prep: out = -x ; xh = x^2 ; inv = 1/(x^2+1)
__global__ __launch_bounds__(256) void prep_kernel(const float* __restrict__ x,
                                                   float* __restrict__ out,
                                                   float* __restrict__ xh,
                                                   float* __restrict__ inv) {
    int i = blockIdx.x * 256 + threadIdx.x;            // 65536 float4s
    float4 v = reinterpret_cast<const float4*>(x)[i];
    reinterpret_cast<float4*>(out)[i] = make_float4(-v.x, -v.y, -v.z, -v.w);
    float4 h = make_float4(v.x * v.x, v.y * v.y, v.z * v.z, v.w * v.w);
    reinterpret_cast<float4*>(xh)[i] = h;
    reinterpret_cast<float4*>(inv)[i] =
        make_float4(1.0f / (h.x + 1.0f), 1.0f / (h.y + 1.0f),
                    1.0f / (h.z + 1.0f), 1.0f / (h.w + 1.0f));
}

__device__ __forceinline__ void gload_lds16(const float* g, float* l, int nt) {
    if (nt)
        __builtin_amdgcn_global_load_lds(
            (const __attribute__((address_space(1))) void*)g,
            (__attribute__((address_space(3))) void*)l, 16, 0, 2 /*NT*/);
    else
        __builtin_amdgcn_global_load_lds(
            (const __attribute__((address_space(1))) void*)g,
            (__attribute__((address_space(3))) void*)l, 16, 0, 0);
}

__global__ __launch_bounds__(TPB) void agg_kernel(const float* __restrict__ A,
                                                  const float* __restrict__ xh,
                                                  const float* __restrict__ inv,
                                                  float* __restrict__ out) {
    // tA[32 rows][128 k]: row r holds logical f4-slot s at phys s^(r&7)
    //   (involution carried on the per-lane SOURCE address; dest lane-linear).
    // tX[128 k][16 d]: k's d-f4-slot v stored at phys v^((k>>3)&3)
    //   -> compute reads: 16-lane broadcast x 4 distinct spans (conflict-free).
    __shared__ float tA[ROWS * KC];   // 16 KiB
    __shared__ float tX[KC * DIM];    // 8 KiB    (24 KiB -> 6 blocks/CU)

    const int tid = threadIdx.x;
    const int l = tid & 63, w = tid >> 6, m = l & 15, q = l >> 4;
    const int rb = blockIdx.x & (NRB - 1);
    const int ks = blockIdx.x >> 9;
    const int r0 = rb * ROWS;
    const size_t k0 = (size_t)ks * KRANGE;

    // ---- A staging: wave w, instr i (0..3) -> rows 8w+2i, 8w+2i+1 ----
    // lane l: hi=l>>5 (row pair half), p31=l&31 (phys f4-slot, 32/row),
    // source logical slot = p31 ^ ((2i+hi)&7)
    const int hi = l >> 5, p31 = l & 31;
    const float* Ab = A + (size_t)(r0 + 8 * w) * NN + k0;
    size_t aoff[4];
    #pragma unroll
    for (int i = 0; i < 4; ++i)
        aoff[i] = (size_t)hi * NN + 4 * (p31 ^ ((2 * i + hi) & 7));

    // ---- X staging: instr j (0..1) covers phys f4-slots (2w+j)*64 + l ----
    // k = (2w+j)*16 + (l>>2); logical v = (l&3) ^ (((2w+j)*2 + (l>>5)) & 3)
    const float* Xc = xh + k0 * DIM;
    int xoff[2];
    #pragma unroll
    for (int j = 0; j < 2; ++j) {
        int kloc = (2 * w + j) * 16 + (l >> 2);
        int sw = ((2 * w + j) * 2 + (l >> 5)) & 3;
        xoff[j] = kloc * 16 + 4 * ((l & 3) ^ sw);
    }

    // ---- compute-side read indices (loop-invariant) ----
    // thread (w,q,m): rows m, m+16; k_loc = 32w+8q+4b+e (b=0..1, e=0..3)
    int rA[2][2];
    #pragma unroll
    for (int j = 0; j < 2; ++j)
        #pragma unroll
        for (int b = 0; b < 2; ++b)
            rA[j][b] = (m + 16 * j) * KC + 4 * ((8 * w + 2 * q + b) ^ (m & 7));
    const int swz = (4 * w + q) & 3;
    int rX[4];
    #pragma unroll
    for (int v = 0; v < 4; ++v)
        rX[v] = (32 * w + 8 * q) * 16 + 4 * (v ^ swz);

    float4 acc[2][4];   // [row j][d-slot v]  (32 floats; no spill risk)
    #pragma unroll
    for (int j = 0; j < 2; ++j)
        #pragma unroll
        for (int v = 0; v < 4; ++v) acc[j][v] = make_float4(0.f, 0.f, 0.f, 0.f);

    for (int t = 0; t < NCH; ++t) {
        __syncthreads();                 // tile t-1 fully consumed by all waves
        // ---- STAGE(t): 4 A-instrs (NT) + 2 X-instrs per wave ----
        {
            const float* sA = Ab + (size_t)t * KC;
            #pragma unroll
            for (int i = 0; i < 4; ++i)
                gload_lds16(sA + (size_t)(2 * i) * NN + aoff[i],
                            &tA[(8 * w + 2 * i) * KC], 1);
            const float* sX = Xc + (size_t)t * (KC * DIM);
            #pragma unroll
            for (int j = 0; j < 2; ++j)
                gload_lds16(sX + xoff[j], &tX[(2 * w + j) * 256], 0);
        }
        __syncthreads();                 // drain: tile t resident
        // ---- COMPUTE(t): LDS-only reads + FMA ----
        #pragma unroll
        for (int b = 0; b < 2; ++b) {
            float4 ar[2];
            ar[0] = *reinterpret_cast<const float4*>(&tA[rA[0][b]]);
            ar[1] = *reinterpret_cast<const float4*>(&tA[rA[1][b]]);
            #pragma unroll
            for (int e = 0; e < 4; ++e) {
                float4 xv[4];
                #pragma unroll
                for (int v = 0; v < 4; ++v)
                    xv[v] = *reinterpret_cast<const float4*>(
                        &tX[rX[v] + (4 * b + e) * 16]);
                #pragma unroll
                for (int j = 0; j < 2; ++j) {
                    const float a = (&ar[j].x)[e];         // e unrolled -> static
                    #pragma unroll
                    for (int v = 0; v < 4; ++v) {
                        acc[j][v].x += a * xv[v].x;
                        acc[j][v].y += a * xv[v].y;
                        acc[j][v].z += a * xv[v].z;
                        acc[j][v].w += a * xv[v].w;
                    }
                }
            }
        }
    }

    // ---- merge the 4 k-phases q (lane bits 4,5) ----
    #pragma unroll
    for (int j = 0; j < 2; ++j)
        #pragma unroll
        for (int v = 0; v < 4; ++v) {
            acc[j][v].x += __shfl_xor(acc[j][v].x, 16);
            acc[j][v].y += __shfl_xor(acc[j][v].y, 16);
            acc[j][v].z += __shfl_xor(acc[j][v].z, 16);
            acc[j][v].w += __shfl_xor(acc[j][v].w, 16);
            acc[j][v].x += __shfl_xor(acc[j][v].x, 32);
            acc[j][v].y += __shfl_xor(acc[j][v].y, 32);
            acc[j][v].z += __shfl_xor(acc[j][v].z, 32);
            acc[j][v].w += __shfl_xor(acc[j][v].w, 32);
        }

    // q==0 lanes write rows m, m+16; waves + KSPLIT merge via atomics
    // (epilogue is linear in agg -> split-K exact)
    if (q == 0) {
        #pragma unroll
        for (int j = 0; j < 2; ++j) {
            const int R = r0 + m + 16 * j;
            const float4* iv4 = reinterpret_cast<const float4*>(inv + (size_t)R * DIM);
            float* orow = out + (size_t)R * DIM;
            #pragma unroll
            for (int v = 0; v < 4; ++v) {
                float4 iv = iv4[v];
                atomicAdd(&orow[4 * v + 0], acc[j][v].x * iv.x);
                atomicAdd(&orow[4 * v + 1], acc[j][v].y * iv.y);
                atomicAdd(&orow[4 * v + 2], acc[j][v].z * iv.z);
                atomicAdd(&orow[4 * v + 3], acc[j][v].w * iv.w);
            }
        }
    }
}

extern "C" void kernel_launch(void* const* d_in, const int* in_sizes, int n_in,
                              void* d_out, int out_size, void* d_ws, size_t ws_size,
                              hipStream_t stream) {
    const float* A = (const float*)d_in[0];
    const float* x = (const float*)d_in[1];
    float* out = (float*)d_out;
    float* xhp = (float*)d_ws;                      // 1 MiB
    float* inv = (float*)d_ws + (size_t)NN * DIM;   // 1 MiB

    prep_kernel<<<(NN * DIM / 4) / 256, 256, 0, stream>>>(x, out, xhp, inv);
    agg_kernel<<<NRB * KSPLIT, TPB, 0, stream>>>(A, xhp, inv, out);
}